// Round 3
// baseline (172.334 us; speedup 1.0000x reference)
//
#include <hip/hip_runtime.h>
#include <hip/hip_bf16.h>
#include <math.h>

#define NRES   4096
#define NBATCH 1024
#define NIN    128
#define NOUT   64
// K layout: [0,4096) x/W_res bf16 | [4096,4224) hiP*hiW | [4224,4352) hiP*loW
//           [4352,4480) loP*hiW | [4480,4544) hiT*hiWo | [4544,4608) hiT*loWo | [4608,4672) loT*hiWo
#define KT     4672
#define KQ     (KT / 4)
#define BM 128
#define BN 128
#define BK 64
#define NT (KT / BK)   // 73 K-steps

typedef __bf16 bf16x8 __attribute__((ext_vector_type(8)));
typedef __bf16 bf16x4 __attribute__((ext_vector_type(4)));
typedef float  f32x4  __attribute__((ext_vector_type(4)));

__device__ __forceinline__ float lo_part(float f) {
    return f - (float)(__bf16)f;
}

__device__ __forceinline__ void gload_lds16(const void* g, void* l) {
    __builtin_amdgcn_global_load_lds(
        (const __attribute__((address_space(1))) unsigned int*)g,
        (__attribute__((address_space(3))) unsigned int*)l, 16, 0, 0);
}

__global__ __launch_bounds__(256) void pack_A4(
    const float* __restrict__ x, const float* __restrict__ passed,
    const float* __restrict__ lastOut, const float* __restrict__ lastPred,
    const float* __restrict__ prob, const float* __restrict__ rand_num,
    __bf16* __restrict__ Abuf)
{
    unsigned id = blockIdx.x * 256u + threadIdx.x;
    if (id >= (unsigned)NBATCH * KQ) return;
    unsigned b = id / KQ;
    unsigned k = (id - b * KQ) * 4u;
    f32x4 v;
    if (k < 4096u) {
        v = *(const f32x4*)(x + (size_t)b * NRES + k);
    } else if (k < 4224u) {
        v = *(const f32x4*)(passed + b * NIN + (k - 4096u));            // hi
    } else if (k < 4352u) {
        v = *(const f32x4*)(passed + b * NIN + (k - 4224u));            // hi (pairs loW)
    } else if (k < 4480u) {
        f32x4 f = *(const f32x4*)(passed + b * NIN + (k - 4352u));      // lo
#pragma unroll
        for (int e = 0; e < 4; ++e) v[e] = lo_part(f[e]);
    } else {
        const float* src = (rand_num[0] < prob[0]) ? lastOut : lastPred;
#pragma unroll
        for (int e = 0; e < 4; ++e) {
            unsigned kk = k + e;
            unsigned j; bool want_lo;
            if (kk < 4544u)      { j = kk - 4480u; want_lo = false; }
            else if (kk < 4608u) { j = kk - 4544u; want_lo = false; }
            else                 { j = kk - 4608u; want_lo = true;  }
            float f = src[j * NBATCH + b];
            v[e] = want_lo ? lo_part(f) : f;
        }
    }
    bf16x4 o;
#pragma unroll
    for (int e = 0; e < 4; ++e) o[e] = (__bf16)v[e];
    *(bf16x4*)(Abuf + (size_t)id * 4u) = o;
}

__global__ __launch_bounds__(256) void pack_B4(
    const float* __restrict__ W_res, const float* __restrict__ W_in,
    const float* __restrict__ W_out, __bf16* __restrict__ Bbuf)
{
    unsigned id = blockIdx.x * 256u + threadIdx.x;
    if (id >= (unsigned)NRES * KQ) return;
    unsigned n = id / KQ;
    unsigned k = (id - n * KQ) * 4u;
    f32x4 v;
    if (k < 4096u) {
        v = *(const f32x4*)(W_res + (size_t)n * NRES + k);
    } else if (k < 4224u) {
        v = *(const f32x4*)(W_in + n * NIN + (k - 4096u));              // hi
    } else if (k < 4352u) {
        f32x4 f = *(const f32x4*)(W_in + n * NIN + (k - 4224u));        // lo (pairs hiP)
#pragma unroll
        for (int e = 0; e < 4; ++e) v[e] = lo_part(f[e]);
    } else if (k < 4480u) {
        v = *(const f32x4*)(W_in + n * NIN + (k - 4352u));              // hi (pairs loP)
    } else if (k < 4544u) {
        v = *(const f32x4*)(W_out + n * NOUT + (k - 4480u));            // hi
    } else if (k < 4608u) {
        f32x4 f = *(const f32x4*)(W_out + n * NOUT + (k - 4544u));      // lo
#pragma unroll
        for (int e = 0; e < 4; ++e) v[e] = lo_part(f[e]);
    } else {
        v = *(const f32x4*)(W_out + n * NOUT + (k - 4608u));            // hi
    }
    bf16x4 o;
#pragma unroll
    for (int e = 0; e < 4; ++e) o[e] = (__bf16)v[e];
    *(bf16x4*)(Bbuf + (size_t)id * 4u) = o;
}

// 4 waves (2x2), wave tile 64x64 (acc[4][4] of 16x16), BK=64.
// A: LDS double-buffer (2x16KB), staged via global_load_lds w/ source-side XOR swizzle.
// B: global->VGPR direct, double-buffered one K-tile ahead (L2-resident panel).
__global__ __launch_bounds__(256) void gemm_kernel(
    const __bf16* __restrict__ Abuf, const __bf16* __restrict__ Bbuf,
    const float* __restrict__ xin, const float* __restrict__ Bin,
    float* __restrict__ out)
{
    __shared__ __align__(16) __bf16 As[2][BM * BK];

    const int t  = threadIdx.x;
    const int l  = t & 63;
    const int w  = t >> 6;   // 0..3
    const int wr = w >> 1;   // 0..1  (64-row slab)
    const int wc = w & 1;    // 0..1  (64-col slab)
    const int bm = blockIdx.y;
    const int bn = blockIdx.x;

    f32x4 acc[4][4] = {};

    // ---- A staging: 1024 16B-chunks per tile, 256 threads -> 4 chunks each.
    // LDS dest LINEAR (global_load_lds requirement); XOR swizzle applied to the
    // global SOURCE column so swizzled ds_reads see correct data (rule #21).
    const __bf16* gA[4];
    int ldoff[4];
#pragma unroll
    for (int j = 0; j < 4; ++j) {
        int ca  = j * 256 + t;             // chunk id 0..1023
        int row = ca >> 3;                 // 0..127
        int cb  = (ca & 7) << 4;           // byte-in-row 0..112
        int cs  = cb ^ ((row & 7) << 4);   // swizzled source byte
        gA[j] = Abuf + (size_t)(bm * BM + row) * KT + (cs >> 1);
        ldoff[j] = ca * 16;
    }

#define STAGE_A(bufi, k0)                                                \
    do {                                                                 \
        _Pragma("unroll")                                                \
        for (int j = 0; j < 4; ++j)                                      \
            gload_lds16(gA[j] + (k0), (char*)As[bufi] + ldoff[j]);       \
    } while (0)

    // ---- A fragment read byte-offsets (swizzled to match staged layout)
    int offA[4][2];
#pragma unroll
    for (int m = 0; m < 4; ++m) {
        int row = wr * 64 + m * 16 + (l & 15);
#pragma unroll
        for (int kk = 0; kk < 2; ++kk) {
            int cb = (kk * 64 + ((l >> 4) << 4)) ^ ((row & 7) << 4);
            offA[m][kk] = row * 128 + cb;
        }
    }

    // ---- B direct-from-global fragment pointers.
    // Fragment: lane reads 16B at Bbuf[col][k0 + kk*32 + (l>>4)*8], col = colbase+(l&15).
    const __bf16* gBn[4];
#pragma unroll
    for (int n = 0; n < 4; ++n) {
        int col = bn * BN + wc * 64 + n * 16 + (l & 15);
        gBn[n] = Bbuf + (size_t)col * KT + ((l >> 4) * 8);
    }

    bf16x8 bv0[4][2], bv1[4][2];

#define LOADB(bv, k0)                                                    \
    do {                                                                 \
        _Pragma("unroll")                                                \
        for (int n = 0; n < 4; ++n)                                      \
            _Pragma("unroll")                                            \
            for (int kk = 0; kk < 2; ++kk)                               \
                bv[n][kk] = *(const bf16x8*)(gBn[n] + (k0) + kk * 32);   \
    } while (0)

#define COMPUTE(bufi, bv)                                                \
    do {                                                                 \
        _Pragma("unroll")                                                \
        for (int kk = 0; kk < 2; ++kk) {                                 \
            bf16x8 af[4];                                                \
            _Pragma("unroll")                                            \
            for (int m = 0; m < 4; ++m)                                  \
                af[m] = *(const bf16x8*)((const char*)As[bufi] + offA[m][kk]); \
            _Pragma("unroll")                                            \
            for (int m = 0; m < 4; ++m)                                  \
                _Pragma("unroll")                                        \
                for (int n = 0; n < 4; ++n)                              \
                    acc[m][n] = __builtin_amdgcn_mfma_f32_16x16x32_bf16( \
                        af[m], bv[n][kk], acc[m][n], 0, 0, 0);           \
        }                                                                \
    } while (0)

    // Prologue: tile 0 into buf0/bv0.
    LOADB(bv0, 0);
    STAGE_A(0, 0);
    asm volatile("s_waitcnt vmcnt(0)" ::: "memory");
    __builtin_amdgcn_s_barrier();
    asm volatile("" ::: "memory");

    // Main: 36 iterations x 2 tiles (tiles 1..72), each half prefetches 1 ahead.
    // Prefetch targets: even half tt+1 (<=71), odd half tt+2 (<=72) -- always valid.
    for (int it = 0; it < 36; ++it) {
        const int tt = 2 * it;
        LOADB(bv1, (tt + 1) * BK);
        STAGE_A(1, (tt + 1) * BK);
        COMPUTE(0, bv0);
        asm volatile("s_waitcnt vmcnt(0)" ::: "memory");
        __builtin_amdgcn_s_barrier();
        asm volatile("" ::: "memory");

        LOADB(bv0, (tt + 2) * BK);
        STAGE_A(0, (tt + 2) * BK);
        COMPUTE(1, bv1);
        asm volatile("s_waitcnt vmcnt(0)" ::: "memory");
        __builtin_amdgcn_s_barrier();
        asm volatile("" ::: "memory");
    }
    COMPUTE(0, bv0);   // tile 72

    // Epilogue: out = 0.1*x + 0.9*tanh(acc + B_in)
    // C/D layout: col = lane&15, row = (lane>>4)*4 + reg  [m89/m91-verified]
    const int col0 = bn * BN + wc * 64 + (l & 15);
    const int row0 = bm * BM + wr * 64 + ((l >> 4) << 2);
#pragma unroll
    for (int m = 0; m < 4; ++m) {
#pragma unroll
        for (int i = 0; i < 4; ++i) {
            int r = row0 + m * 16 + i;
            const float* xr   = xin + (size_t)r * NRES;
            float*       orow = out + (size_t)r * NRES;
#pragma unroll
            for (int n = 0; n < 4; ++n) {
                int c = col0 + n * 16;
                float pre = acc[m][n][i] + Bin[c];
                orow[c] = 0.1f * xr[c] + 0.9f * tanhf(pre);
            }
        }
    }
#undef STAGE_A
#undef LOADB
#undef COMPUTE
}

extern "C" void kernel_launch(void* const* d_in, const int* in_sizes, int n_in,
                              void* d_out, int out_size, void* d_ws, size_t ws_size,
                              hipStream_t stream) {
    (void)in_sizes; (void)n_in; (void)out_size; (void)ws_size;
    const float* passed     = (const float*)d_in[0];
    const float* lastOutput = (const float*)d_in[1];
    const float* lastPred   = (const float*)d_in[2];
    const float* x          = (const float*)d_in[3];
    const float* prob       = (const float*)d_in[4];
    const float* rand_num   = (const float*)d_in[5];
    const float* W_in       = (const float*)d_in[6];
    const float* W_res      = (const float*)d_in[7];
    const float* W_out      = (const float*)d_in[8];
    const float* B_in       = (const float*)d_in[9];
    float* out = (float*)d_out;

    __bf16* Abuf = (__bf16*)d_ws;                                    // 1024*4672*2 B
    __bf16* Bbuf = (__bf16*)((char*)d_ws + (size_t)NBATCH * KT * 2); // 4096*4672*2 B

    pack_A4<<<(NBATCH * KQ) / 256, 256, 0, stream>>>(
        x, passed, lastOutput, lastPred, prob, rand_num, Abuf);
    pack_B4<<<(NRES * KQ) / 256, 256, 0, stream>>>(
        W_res, W_in, W_out, Bbuf);

    dim3 grid(NRES / BN, NBATCH / BM);
    gemm_kernel<<<grid, 256, 0, stream>>>(Abuf, Bbuf, x, B_in, out);
}

// Round 4
// 114.964 us; speedup vs baseline: 1.4990x; 1.4990x over previous
//
#include <hip/hip_runtime.h>
#include <hip/hip_bf16.h>
#include <math.h>

#define NRES   4096
#define NBATCH 1024
#define NIN    128
#define NOUT   64
// K layout: [0,4096) x/W_res bf16 | [4096,4224) hiP*hiW | [4224,4352) hiP*loW
//           [4352,4480) loP*hiW | [4480,4544) hiT*hiWo | [4544,4608) hiT*loWo | [4608,4672) loT*hiWo
#define KT     4672
#define KQ     (KT / 4)
#define BM 64
#define BN 128
#define BK 64
#define NT (KT / BK)   // 73 K-steps

typedef __bf16 bf16x8 __attribute__((ext_vector_type(8)));
typedef __bf16 bf16x4 __attribute__((ext_vector_type(4)));
typedef float  f32x4  __attribute__((ext_vector_type(4)));

__device__ __forceinline__ float lo_part(float f) {
    return f - (float)(__bf16)f;
}

__device__ __forceinline__ void gload_lds16(const void* g, void* l) {
    __builtin_amdgcn_global_load_lds(
        (const __attribute__((address_space(1))) unsigned int*)g,
        (__attribute__((address_space(3))) unsigned int*)l, 16, 0, 0);
}

__global__ __launch_bounds__(256) void pack_A4(
    const float* __restrict__ x, const float* __restrict__ passed,
    const float* __restrict__ lastOut, const float* __restrict__ lastPred,
    const float* __restrict__ prob, const float* __restrict__ rand_num,
    __bf16* __restrict__ Abuf)
{
    unsigned id = blockIdx.x * 256u + threadIdx.x;
    if (id >= (unsigned)NBATCH * KQ) return;
    unsigned b = id / KQ;
    unsigned k = (id - b * KQ) * 4u;
    f32x4 v;
    if (k < 4096u) {
        v = *(const f32x4*)(x + (size_t)b * NRES + k);
    } else if (k < 4224u) {
        v = *(const f32x4*)(passed + b * NIN + (k - 4096u));            // hi
    } else if (k < 4352u) {
        v = *(const f32x4*)(passed + b * NIN + (k - 4224u));            // hi (pairs loW)
    } else if (k < 4480u) {
        f32x4 f = *(const f32x4*)(passed + b * NIN + (k - 4352u));      // lo
#pragma unroll
        for (int e = 0; e < 4; ++e) v[e] = lo_part(f[e]);
    } else {
        const float* src = (rand_num[0] < prob[0]) ? lastOut : lastPred;
#pragma unroll
        for (int e = 0; e < 4; ++e) {
            unsigned kk = k + e;
            unsigned j; bool want_lo;
            if (kk < 4544u)      { j = kk - 4480u; want_lo = false; }
            else if (kk < 4608u) { j = kk - 4544u; want_lo = false; }
            else                 { j = kk - 4608u; want_lo = true;  }
            float f = src[j * NBATCH + b];
            v[e] = want_lo ? lo_part(f) : f;
        }
    }
    bf16x4 o;
#pragma unroll
    for (int e = 0; e < 4; ++e) o[e] = (__bf16)v[e];
    *(bf16x4*)(Abuf + (size_t)id * 4u) = o;
}

__global__ __launch_bounds__(256) void pack_B4(
    const float* __restrict__ W_res, const float* __restrict__ W_in,
    const float* __restrict__ W_out, __bf16* __restrict__ Bbuf)
{
    unsigned id = blockIdx.x * 256u + threadIdx.x;
    if (id >= (unsigned)NRES * KQ) return;
    unsigned n = id / KQ;
    unsigned k = (id - n * KQ) * 4u;
    f32x4 v;
    if (k < 4096u) {
        v = *(const f32x4*)(W_res + (size_t)n * NRES + k);
    } else if (k < 4224u) {
        v = *(const f32x4*)(W_in + n * NIN + (k - 4096u));              // hi
    } else if (k < 4352u) {
        f32x4 f = *(const f32x4*)(W_in + n * NIN + (k - 4224u));        // lo (pairs hiP)
#pragma unroll
        for (int e = 0; e < 4; ++e) v[e] = lo_part(f[e]);
    } else if (k < 4480u) {
        v = *(const f32x4*)(W_in + n * NIN + (k - 4352u));              // hi (pairs loP)
    } else if (k < 4544u) {
        v = *(const f32x4*)(W_out + n * NOUT + (k - 4480u));            // hi
    } else if (k < 4608u) {
        f32x4 f = *(const f32x4*)(W_out + n * NOUT + (k - 4544u));      // lo
#pragma unroll
        for (int e = 0; e < 4; ++e) v[e] = lo_part(f[e]);
    } else {
        v = *(const f32x4*)(W_out + n * NOUT + (k - 4608u));            // hi
    }
    bf16x4 o;
#pragma unroll
    for (int e = 0; e < 4; ++e) o[e] = (__bf16)v[e];
    *(bf16x4*)(Bbuf + (size_t)id * 4u) = o;
}

// 64x128 tile, 4 waves of 64x32, BK=64. Grid 512 blocks = 2 blocks/CU so two
// independent barrier domains overlap (one computes while the other drains).
// 3-deep LDS pipeline (A 8KB + B 16KB per buf, 72KB total), counted vmcnt.
__global__ __launch_bounds__(256) void gemm_kernel(
    const __bf16* __restrict__ Abuf, const __bf16* __restrict__ Bbuf,
    const float* __restrict__ xin, const float* __restrict__ Bin,
    float* __restrict__ out)
{
    __shared__ __align__(16) __bf16 As[3][BM * BK];
    __shared__ __align__(16) __bf16 Bs[3][BN * BK];

    const int t  = threadIdx.x;
    const int l  = t & 63;
    const int wc = t >> 6;   // wave id 0..3 -> 32-col slab
    const int bm = blockIdx.y;
    const int bn = blockIdx.x;

    f32x4 acc[4][2] = {};

    // ---- staging: A 512 chunks (2/thread), B 1024 chunks (4/thread), 16B each.
    // LDS dest LINEAR (global_load_lds requirement); XOR swizzle applied to the
    // global SOURCE column so swizzled ds_reads see correct data (rule #21).
    const __bf16* gA[2];
    const __bf16* gB[4];
    int ldoffA[2], ldoffB[4];
#pragma unroll
    for (int j = 0; j < 2; ++j) {
        int ca  = j * 256 + t;             // chunk id 0..511
        int row = ca >> 3;                 // 0..63
        int cb  = (ca & 7) << 4;           // byte-in-row 0..112
        int cs  = cb ^ ((row & 7) << 4);   // swizzled source byte
        gA[j] = Abuf + (size_t)(bm * BM + row) * KT + (cs >> 1);
        ldoffA[j] = ca * 16;
    }
#pragma unroll
    for (int j = 0; j < 4; ++j) {
        int ca  = j * 256 + t;             // chunk id 0..1023
        int row = ca >> 3;                 // 0..127
        int cb  = (ca & 7) << 4;
        int cs  = cb ^ ((row & 7) << 4);
        gB[j] = Bbuf + (size_t)(bn * BN + row) * KT + (cs >> 1);
        ldoffB[j] = ca * 16;
    }

// 6 gload_lds per thread per stage (2 A + 4 B)
#define STAGE(bufi, k0)                                                  \
    do {                                                                 \
        _Pragma("unroll")                                                \
        for (int j = 0; j < 2; ++j)                                      \
            gload_lds16(gA[j] + (k0), (char*)As[bufi] + ldoffA[j]);      \
        _Pragma("unroll")                                                \
        for (int j = 0; j < 4; ++j)                                      \
            gload_lds16(gB[j] + (k0), (char*)Bs[bufi] + ldoffB[j]);      \
    } while (0)

    // ---- fragment read byte-offsets (swizzled to match staged layout)
    int offA[4][2], offB[2][2];
#pragma unroll
    for (int m = 0; m < 4; ++m) {
        int row = m * 16 + (l & 15);       // wave spans all 64 A-rows
#pragma unroll
        for (int kk = 0; kk < 2; ++kk) {
            int cb = (kk * 64 + ((l >> 4) << 4)) ^ ((row & 7) << 4);
            offA[m][kk] = row * 128 + cb;
        }
    }
#pragma unroll
    for (int n = 0; n < 2; ++n) {
        int row = wc * 32 + n * 16 + (l & 15);
#pragma unroll
        for (int kk = 0; kk < 2; ++kk) {
            int cb = (kk * 64 + ((l >> 4) << 4)) ^ ((row & 7) << 4);
            offB[n][kk] = row * 128 + cb;
        }
    }

#define COMPUTE(bufi)                                                    \
    do {                                                                 \
        _Pragma("unroll")                                                \
        for (int kk = 0; kk < 2; ++kk) {                                 \
            bf16x8 af[4], bv[2];                                         \
            _Pragma("unroll")                                            \
            for (int m = 0; m < 4; ++m)                                  \
                af[m] = *(const bf16x8*)((const char*)As[bufi] + offA[m][kk]); \
            _Pragma("unroll")                                            \
            for (int n = 0; n < 2; ++n)                                  \
                bv[n] = *(const bf16x8*)((const char*)Bs[bufi] + offB[n][kk]); \
            _Pragma("unroll")                                            \
            for (int m = 0; m < 4; ++m)                                  \
                _Pragma("unroll")                                        \
                for (int n = 0; n < 2; ++n)                              \
                    acc[m][n] = __builtin_amdgcn_mfma_f32_16x16x32_bf16( \
                        af[m], bv[n], acc[m][n], 0, 0, 0);               \
        }                                                                \
    } while (0)

    // Prologue: stage tiles 0 and 1; wait until tile 0's 6 loads done
    // (tile 1's 6 may remain in flight).
    STAGE(0, 0);
    STAGE(1, BK);
    asm volatile("s_waitcnt vmcnt(6)" ::: "memory");
    __builtin_amdgcn_s_barrier();
    asm volatile("" ::: "memory");

    for (int tt = 0; tt < NT - 1; ++tt) {
        const int cur = tt % 3;
        const int nxt = (tt + 2) % 3;
        if (tt + 2 < NT) {
            STAGE(nxt, (tt + 2) * BK);
            COMPUTE(cur);
            asm volatile("s_waitcnt vmcnt(6)" ::: "memory"); // tile tt+1 landed; tt+2 in flight
        } else {
            COMPUTE(cur);
            asm volatile("s_waitcnt vmcnt(0)" ::: "memory"); // drain last tile
        }
        __builtin_amdgcn_s_barrier();
        asm volatile("" ::: "memory");
    }
    COMPUTE((NT - 1) % 3);

    // Epilogue: out = 0.1*x + 0.9*tanh(acc + B_in)
    // C/D layout: col = lane&15, row = (lane>>4)*4 + reg  [m89/m91-verified]
    const int col0 = bn * BN + wc * 32 + (l & 15);
    const int row0 = bm * BM + ((l >> 4) << 2);
#pragma unroll
    for (int m = 0; m < 4; ++m) {
#pragma unroll
        for (int i = 0; i < 4; ++i) {
            int r = row0 + m * 16 + i;
            const float* xr   = xin + (size_t)r * NRES;
            float*       orow = out + (size_t)r * NRES;
#pragma unroll
            for (int n = 0; n < 2; ++n) {
                int c = col0 + n * 16;
                float pre = acc[m][n][i] + Bin[c];
                orow[c] = 0.1f * xr[c] + 0.9f * tanhf(pre);
            }
        }
    }
#undef STAGE
#undef COMPUTE
}

extern "C" void kernel_launch(void* const* d_in, const int* in_sizes, int n_in,
                              void* d_out, int out_size, void* d_ws, size_t ws_size,
                              hipStream_t stream) {
    (void)in_sizes; (void)n_in; (void)out_size; (void)ws_size;
    const float* passed     = (const float*)d_in[0];
    const float* lastOutput = (const float*)d_in[1];
    const float* lastPred   = (const float*)d_in[2];
    const float* x          = (const float*)d_in[3];
    const float* prob       = (const float*)d_in[4];
    const float* rand_num   = (const float*)d_in[5];
    const float* W_in       = (const float*)d_in[6];
    const float* W_res      = (const float*)d_in[7];
    const float* W_out      = (const float*)d_in[8];
    const float* B_in       = (const float*)d_in[9];
    float* out = (float*)d_out;

    __bf16* Abuf = (__bf16*)d_ws;                                    // 1024*4672*2 B
    __bf16* Bbuf = (__bf16*)((char*)d_ws + (size_t)NBATCH * KT * 2); // 4096*4672*2 B

    pack_A4<<<(NBATCH * KQ) / 256, 256, 0, stream>>>(
        x, passed, lastOutput, lastPred, prob, rand_num, Abuf);
    pack_B4<<<(NRES * KQ) / 256, 256, 0, stream>>>(
        W_res, W_in, W_out, Bbuf);

    dim3 grid(NRES / BN, NBATCH / BM);
    gemm_kernel<<<grid, 256, 0, stream>>>(Abuf, Bbuf, x, B_in, out);
}